// Round 1
// baseline (26.709 us; speedup 1.0000x reference)
//
#include <hip/hip_runtime.h>

#define B_ 4
#define T_ 512
#define D_ 2048
#define H_ 1024
#define E_ 2

__device__ __forceinline__ float waveReduceSum(float v) {
    #pragma unroll
    for (int o = 32; o > 0; o >>= 1) v += __shfl_down(v, o, 64);
    return v;
}

// Block reduce for 256 threads (4 waves). Result valid in thread 0.
__device__ __forceinline__ float blockReduceSum256(float v, float* lds) {
    int lane = threadIdx.x & 63;
    int wid  = threadIdx.x >> 6;
    v = waveReduceSum(v);
    if (lane == 0) lds[wid] = v;
    __syncthreads();
    float r = 0.f;
    if (threadIdx.x == 0) {
        r = lds[0] + lds[1] + lds[2] + lds[3];
    }
    __syncthreads();
    return r;
}

// w2s[e,h] = sum_d W2[e,h,d].  One block per row (E*H rows), row length D.
__global__ void k_w2sum(const float* __restrict__ W2, float* __restrict__ w2s) {
    __shared__ float lds[4];
    int row = blockIdx.x;                       // e*H + h
    const float* p = W2 + (size_t)row * D_;
    float acc = 0.f;
    for (int i = threadIdx.x * 4; i < D_; i += blockDim.x * 4) {
        float4 v = *reinterpret_cast<const float4*>(p + i);
        acc += (v.x + v.y) + (v.z + v.w);
    }
    acc = blockReduceSum256(acc, lds);
    if (threadIdx.x == 0) w2s[row] = acc;
}

// v[e,d] = sum_h W1[e,d,h] * w2s[e,h].  One block per row (E*D rows), row length H.
__global__ void k_vred(const float* __restrict__ W1, const float* __restrict__ w2s,
                       float* __restrict__ v) {
    __shared__ float lds[4];
    int row = blockIdx.x;                       // e*D + d
    int e = row / D_;
    const float* p = W1 + (size_t)row * H_;
    const float* w = w2s + e * H_;
    float acc = 0.f;
    for (int i = threadIdx.x * 4; i < H_; i += blockDim.x * 4) {
        float4 a = *reinterpret_cast<const float4*>(p + i);
        float4 b = *reinterpret_cast<const float4*>(w + i);
        acc += a.x * b.x + a.y * b.y + a.z * b.z + a.w * b.w;
    }
    acc = blockReduceSum256(acc, lds);
    if (threadIdx.x == 0) v[row] = acc;
}

// c[e] = sum_h b1[e,h]*w2s[e,h] + sum_d b2[e,d].  One block per expert.
__global__ void k_cbias(const float* __restrict__ b1, const float* __restrict__ w2s,
                        const float* __restrict__ b2, float* __restrict__ c) {
    __shared__ float lds[4];
    int e = blockIdx.x;
    float acc = 0.f;
    for (int i = threadIdx.x; i < H_; i += blockDim.x)
        acc += b1[e * H_ + i] * w2s[e * H_ + i];
    for (int i = threadIdx.x; i < D_; i += blockDim.x)
        acc += b2[e * D_ + i];
    acc = blockReduceSum256(acc, lds);
    if (threadIdx.x == 0) c[e] = acc;
}

// Per token: gate logits (x.Wg), both expert reduced-dots (x.v[e]), softmax/argmax,
// s[b,t] = gate * (dot[idx] + c[idx]).  One block (256 thr) per token, single x pass.
__global__ void k_token(const float* __restrict__ x, const float* __restrict__ Wg,
                        const float* __restrict__ v, const float* __restrict__ c,
                        float* __restrict__ s) {
    __shared__ float lds[4][4];
    int bt = blockIdx.x;                        // b*T + t
    const float* xp = x + (size_t)bt * D_;
    float g0 = 0.f, g1 = 0.f, d0 = 0.f, d1 = 0.f;
    for (int i = threadIdx.x * 4; i < D_; i += blockDim.x * 4) {
        float4 xv   = *reinterpret_cast<const float4*>(xp + i);
        float4 v0   = *reinterpret_cast<const float4*>(v + i);
        float4 v1   = *reinterpret_cast<const float4*>(v + D_ + i);
        float4 wg01 = *reinterpret_cast<const float4*>(Wg + i * 2);      // d=i, i+1
        float4 wg23 = *reinterpret_cast<const float4*>(Wg + i * 2 + 4);  // d=i+2, i+3
        g0 += xv.x * wg01.x + xv.y * wg01.z + xv.z * wg23.x + xv.w * wg23.z;
        g1 += xv.x * wg01.y + xv.y * wg01.w + xv.z * wg23.y + xv.w * wg23.w;
        d0 += xv.x * v0.x + xv.y * v0.y + xv.z * v0.z + xv.w * v0.w;
        d1 += xv.x * v1.x + xv.y * v1.y + xv.z * v1.z + xv.w * v1.w;
    }
    // wave-level butterfly-free reduce of 4 values, then cross-wave via LDS
    #pragma unroll
    for (int o = 32; o > 0; o >>= 1) {
        g0 += __shfl_down(g0, o, 64);
        g1 += __shfl_down(g1, o, 64);
        d0 += __shfl_down(d0, o, 64);
        d1 += __shfl_down(d1, o, 64);
    }
    int lane = threadIdx.x & 63;
    int wid  = threadIdx.x >> 6;
    if (lane == 0) {
        lds[wid][0] = g0; lds[wid][1] = g1; lds[wid][2] = d0; lds[wid][3] = d1;
    }
    __syncthreads();
    if (threadIdx.x == 0) {
        float G0 = 0.f, G1 = 0.f, Dt0 = 0.f, Dt1 = 0.f;
        #pragma unroll
        for (int w = 0; w < 4; ++w) {
            G0 += lds[w][0]; G1 += lds[w][1]; Dt0 += lds[w][2]; Dt1 += lds[w][3];
        }
        int e = (G1 > G0) ? 1 : 0;              // jnp.argmax: first index on tie
        float m  = fmaxf(G0, G1);
        float p0 = expf(G0 - m), p1 = expf(G1 - m);
        float gate = ((e == 0) ? p0 : p1) / (p0 + p1);
        float dot  = (e == 0) ? Dt0 : Dt1;
        s[bt] = gate * (dot + c[e]);
    }
}

// out[b,t] = s[b,t] - max_t - log(sum_t exp(s - max_t)).  One block (512 thr) per b.
__global__ void k_lsm(const float* __restrict__ s, float* __restrict__ out) {
    __shared__ float lds[8];
    int b = blockIdx.x;
    int t = threadIdx.x;                        // 512 threads, 8 waves
    int lane = t & 63, wid = t >> 6;
    float val = s[b * T_ + t];

    float m = val;
    #pragma unroll
    for (int o = 1; o < 64; o <<= 1) m = fmaxf(m, __shfl_xor(m, o, 64));
    if (lane == 0) lds[wid] = m;
    __syncthreads();
    m = lds[0];
    #pragma unroll
    for (int w = 1; w < 8; ++w) m = fmaxf(m, lds[w]);
    __syncthreads();

    float ex = expf(val - m);
    float sum = ex;
    #pragma unroll
    for (int o = 1; o < 64; o <<= 1) sum += __shfl_xor(sum, o, 64);
    if (lane == 0) lds[wid] = sum;
    __syncthreads();
    sum = 0.f;
    #pragma unroll
    for (int w = 0; w < 8; ++w) sum += lds[w];

    out[b * T_ + t] = val - m - logf(sum);
}

extern "C" void kernel_launch(void* const* d_in, const int* in_sizes, int n_in,
                              void* d_out, int out_size, void* d_ws, size_t ws_size,
                              hipStream_t stream) {
    (void)in_sizes; (void)n_in; (void)out_size; (void)ws_size;
    const float* x  = (const float*)d_in[0];
    const float* Wg = (const float*)d_in[1];
    const float* W1 = (const float*)d_in[2];
    const float* b1 = (const float*)d_in[3];
    const float* W2 = (const float*)d_in[4];
    const float* b2 = (const float*)d_in[5];
    float* out = (float*)d_out;

    float* ws  = (float*)d_ws;
    float* w2s = ws;            // [E,H]  = 2048 floats
    float* v   = ws + 2048;     // [E,D]  = 4096 floats
    float* c   = ws + 6144;     // [E]    = 2 floats
    float* s   = ws + 6160;     // [B,T]  = 2048 floats (16B-aligned offset)

    k_w2sum<<<E_ * H_, 256, 0, stream>>>(W2, w2s);
    k_vred <<<E_ * D_, 256, 0, stream>>>(W1, w2s, v);
    k_cbias<<<E_,      256, 0, stream>>>(b1, w2s, b2, c);
    k_token<<<B_ * T_, 256, 0, stream>>>(x, Wg, v, c, s);
    k_lsm  <<<B_,      512, 0, stream>>>(s, out);
}